// Round 1
// 793.408 us; speedup vs baseline: 1.1201x; 1.1201x over previous
//
#include <hip/hip_runtime.h>
#include <hip/hip_bf16.h>
#include <cstddef>
#include <cstdint>

// Problem constants
constexpr int B_  = 8;
constexpr int C_  = 512;
constexpr int KC_ = 256;
constexpr int M_  = 19;
constexpr int P_  = 128 * 128;  // 16384 pixels

typedef short frag8 __attribute__((ext_vector_type(8)));           // 8 bf16 (4 VGPRs)
typedef float f32x4 __attribute__((ext_vector_type(4)));           // 4 fp32 acc
typedef unsigned short u16x8 __attribute__((ext_vector_type(8)));  // 8 bf16

__device__ __forceinline__ unsigned pk_bf16(float a, float b) {
    union { __hip_bfloat162 h; unsigned u; } cv;
    cv.h = __float22bfloat162_rn(make_float2(a, b));
    return cv.u;
}
__device__ __forceinline__ ushort bf16_1(float a) {
    union { __hip_bfloat16 h; ushort u; } cv;
    cv.h = __float2bfloat16(a);
    return cv.u;
}
__device__ __forceinline__ float bf16_f(ushort u) {
    return __uint_as_float(((unsigned)u) << 16);
}

// global(16B per lane, per-lane address) -> LDS (wave-uniform base + lane*16)
__device__ __forceinline__ void gll16(const ushort* g, ushort* l) {
    __builtin_amdgcn_global_load_lds(
        (__attribute__((address_space(1))) void*)(ushort*)g,
        (__attribute__((address_space(3))) void*)l, 16, 0, 0);
}

// ---------------------------------------------------------------------------
// k/v projection (fp32, tiny): proxy [B,C,M] -> K,V [B,KC,M]
// ---------------------------------------------------------------------------
__device__ __forceinline__ void two_stage_proj(
    const float* __restrict__ pS, float* __restrict__ t1,
    const float* __restrict__ W1, const float* __restrict__ s1, const float* __restrict__ b1,
    const float* __restrict__ W2, const float* __restrict__ s2, const float* __restrict__ b2,
    float* __restrict__ outg, int b, int tid)
{
    float acc[M_];
#pragma unroll
    for (int m = 0; m < M_; ++m) acc[m] = 0.f;
    const float4* wrow = reinterpret_cast<const float4*>(W1 + (size_t)tid * C_);
    for (int c4 = 0; c4 < C_ / 4; ++c4) {
        float4 w = wrow[c4];
        const float* pr = pS + c4 * 4 * M_;
#pragma unroll
        for (int m = 0; m < M_; ++m) acc[m] = fmaf(w.x, pr[m], acc[m]);
#pragma unroll
        for (int m = 0; m < M_; ++m) acc[m] = fmaf(w.y, pr[M_ + m], acc[m]);
#pragma unroll
        for (int m = 0; m < M_; ++m) acc[m] = fmaf(w.z, pr[2 * M_ + m], acc[m]);
#pragma unroll
        for (int m = 0; m < M_; ++m) acc[m] = fmaf(w.w, pr[3 * M_ + m], acc[m]);
    }
    float s = s1[tid], bb = b1[tid];
    __syncthreads();
#pragma unroll
    for (int m = 0; m < M_; ++m) t1[tid * M_ + m] = fmaxf(fmaf(acc[m], s, bb), 0.f);
    __syncthreads();
#pragma unroll
    for (int m = 0; m < M_; ++m) acc[m] = 0.f;
    const float4* wrow2 = reinterpret_cast<const float4*>(W2 + (size_t)tid * KC_);
    for (int c4 = 0; c4 < KC_ / 4; ++c4) {
        float4 w = wrow2[c4];
        const float* tr = t1 + c4 * 4 * M_;
#pragma unroll
        for (int m = 0; m < M_; ++m) acc[m] = fmaf(w.x, tr[m], acc[m]);
#pragma unroll
        for (int m = 0; m < M_; ++m) acc[m] = fmaf(w.y, tr[M_ + m], acc[m]);
#pragma unroll
        for (int m = 0; m < M_; ++m) acc[m] = fmaf(w.z, tr[2 * M_ + m], acc[m]);
#pragma unroll
        for (int m = 0; m < M_; ++m) acc[m] = fmaf(w.w, tr[3 * M_ + m], acc[m]);
    }
    s = s2[tid]; bb = b2[tid];
#pragma unroll
    for (int m = 0; m < M_; ++m)
        outg[((size_t)b * KC_ + tid) * M_ + m] = fmaxf(fmaf(acc[m], s, bb), 0.f);
}

__device__ __forceinline__ void cvt_w(const float* __restrict__ s, ushort* __restrict__ d,
                                      int n4, int cid, int nb) {
    for (int i = cid * 256 + (int)threadIdx.x; i < n4; i += nb * 256) {
        float4 f = ((const float4*)s)[i];
        ushort4 h;
        h.x = bf16_1(f.x); h.y = bf16_1(f.y); h.z = bf16_1(f.z); h.w = bf16_1(f.w);
        ((ushort4*)d)[i] = h;
    }
}

// Fused front: blocks 0..15 do K/V projections (K or V per block, 2x parallel
// vs before); blocks 16.. convert W_p1/W_p2/W_u fp32 -> bf16 row-major [O][K].
__global__ __launch_bounds__(256) void front_kernel(
    const float* __restrict__ proxy,
    const float* __restrict__ Wo1, const float* __restrict__ so1, const float* __restrict__ bo1,
    const float* __restrict__ Wo2, const float* __restrict__ so2, const float* __restrict__ bo2,
    const float* __restrict__ Wd1, const float* __restrict__ sd1, const float* __restrict__ bd1,
    const float* __restrict__ Wd2, const float* __restrict__ sd2, const float* __restrict__ bd2,
    float* __restrict__ Kg, float* __restrict__ Vg,
    const float* __restrict__ Wp1f, const float* __restrict__ Wp2f, const float* __restrict__ Wuf,
    ushort* __restrict__ Wp1b, ushort* __restrict__ Wp2b, ushort* __restrict__ Wub)
{
    __shared__ float pS[C_ * M_];
    __shared__ float t1[KC_ * M_];
    const int bx = blockIdx.x, tid = threadIdx.x;
    if (bx < 16) {
        const int b = bx >> 1;
        for (int i = tid; i < C_ * M_; i += 256) pS[i] = proxy[(size_t)b * C_ * M_ + i];
        __syncthreads();
        if (bx & 1)
            two_stage_proj(pS, t1, Wd1, sd1, bd1, Wd2, sd2, bd2, Vg, b, tid);
        else
            two_stage_proj(pS, t1, Wo1, so1, bo1, Wo2, so2, bo2, Kg, b, tid);
    } else {
        const int cid = bx - 16, nb = (int)gridDim.x - 16;
        cvt_w(Wp1f, Wp1b, KC_ * C_ / 4, cid, nb);
        cvt_w(Wp2f, Wp2b, KC_ * KC_ / 4, cid, nb);
        cvt_w(Wuf,  Wub,  C_ * KC_ / 4, cid, nb);
    }
}

// ---------------------------------------------------------------------------
// Step 2: q1 = CBR(x, W_p1).  x fp32 [B][C][P] (reg-staged + cvt), W bf16.
// Output TILED: q1 [B][P][KC] bf16 (pixel-major) -> enables global_load_lds
// in the downstream GEMMs and contiguous per-thread rows in attention.
// 128x128 tile, BK=32, 4 waves x (4x4) 16x16x32 MFMAs. XCD-chunked swizzle.
// ---------------------------------------------------------------------------
__global__ __launch_bounds__(256) void cbr_f32in(
    const ushort* __restrict__ Wb, const float* __restrict__ X,
    const float* __restrict__ sc, const float* __restrict__ bi,
    ushort* __restrict__ Y)
{
    constexpr int K = C_;   // 512
    constexpr int O = KC_;  // 256
    __shared__ __align__(16) ushort As[128][40];
    __shared__ __align__(16) ushort Bs[128][40];

    const int tid = threadIdx.x;
    // bijective XCD-chunked swizzle (grid = 2048 = 8*256)
    const unsigned bid = blockIdx.x;
    const unsigned swz = (bid & 7) * (gridDim.x >> 3) + (bid >> 3);
    const int m0 = (int)(swz & 1) * 128;
    const int n0 = (int)((swz >> 1) & 127) * 128;
    const int b  = (int)(swz >> 8);

    const int wave = tid >> 6, lane = tid & 63;
    const int quad = lane >> 4, l15 = lane & 15;
    const int mq = (wave & 1) * 64, nq = (wave >> 1) * 64;

    const int am  = tid >> 1;                 // A row 0..127
    const int akh = (tid & 1) * 16;           // A k-half
    const int pp  = (tid & 63) * 2;           // B p-pair 0..126
    const int bkg = (tid >> 6) * 8;           // B k-group 0,8,16,24

    const ushort* Wp = Wb + (size_t)(m0 + am) * K + akh;
    const float*  Xf = X + (size_t)b * K * P_ + n0 + pp;

    f32x4 acc[4][4];
#pragma unroll
    for (int i = 0; i < 4; ++i)
#pragma unroll
        for (int j = 0; j < 4; ++j) acc[i][j] = {0.f, 0.f, 0.f, 0.f};

    for (int k0 = 0; k0 < K; k0 += 32) {
        // global loads issued before barrier (overlap prev MFMAs)
        u16x8 wa0 = *(const u16x8*)(Wp + k0);
        u16x8 wa1 = *(const u16x8*)(Wp + k0 + 8);
        float2 xr[8];
#pragma unroll
        for (int j = 0; j < 8; ++j)
            xr[j] = *(const float2*)(Xf + (size_t)(k0 + bkg + j) * P_);
        unsigned bd0[4], bd1[4];
#pragma unroll
        for (int i = 0; i < 4; ++i) {
            bd0[i] = pk_bf16(xr[2 * i].x, xr[2 * i + 1].x);   // row pp
            bd1[i] = pk_bf16(xr[2 * i].y, xr[2 * i + 1].y);   // row pp+1
        }

        __syncthreads();   // prev tile's readers done
        *(u16x8*)(&As[am][akh])     = wa0;
        *(u16x8*)(&As[am][akh + 8]) = wa1;
        *(int4*)(&Bs[pp][bkg])      = *(int4*)bd0;
        *(int4*)(&Bs[pp + 1][bkg])  = *(int4*)bd1;
        __syncthreads();

        frag8 af[4], bfv[4];
#pragma unroll
        for (int f = 0; f < 4; ++f) {
            af[f]  = *(const frag8*)(&As[mq + f * 16 + l15][quad * 8]);
            bfv[f] = *(const frag8*)(&Bs[nq + f * 16 + l15][quad * 8]);
        }
#pragma unroll
        for (int i = 0; i < 4; ++i)
#pragma unroll
            for (int j = 0; j < 4; ++j)
                acc[i][j] = __builtin_amdgcn_mfma_f32_16x16x32_bf16(
                    af[i], bfv[j], acc[i][j], 0, 0, 0);
    }

    // epilogue: relu(s*acc+b) -> Y[b][p][o] bf16, 4 o-contig per 8B store
#pragma unroll
    for (int i = 0; i < 4; ++i) {
        const int o0 = m0 + mq + i * 16 + quad * 4;
        float s4[4], b4[4];
#pragma unroll
        for (int r = 0; r < 4; ++r) { s4[r] = sc[o0 + r]; b4[r] = bi[o0 + r]; }
#pragma unroll
        for (int j = 0; j < 4; ++j) {
            const int p = n0 + nq + j * 16 + l15;
            float v0 = fmaxf(fmaf(acc[i][j][0], s4[0], b4[0]), 0.f);
            float v1 = fmaxf(fmaf(acc[i][j][1], s4[1], b4[1]), 0.f);
            float v2 = fmaxf(fmaf(acc[i][j][2], s4[2], b4[2]), 0.f);
            float v3 = fmaxf(fmaf(acc[i][j][3], s4[3], b4[3]), 0.f);
            uint2 w; w.x = pk_bf16(v0, v1); w.y = pk_bf16(v2, v3);
            *(uint2*)(Y + ((size_t)b * P_ + p) * O + o0) = w;
        }
    }
}

// ---------------------------------------------------------------------------
// Steps 3 & 5: CBR-GEMM with global_load_lds(16B) + 2-phase pipeline.
// W bf16 [O][K] row-major, X bf16 [B][P][K] pixel-major.
// LDS tile per operand: 128 rows x 32 k, double-buffered (32 KB total).
// Swizzle: octet j of row r stored at (j>>1)*2048 + r*16 + ((j&1)^((r>>2)&1))*8
// (ushorts).  gll dest is linear (wave base + lane*16); the source-side octet
// permutation jx=(t&1)^((t>>3)&1) realizes the swizzle (rule #21: both sides).
// Fragment ds_read_b128 lands 2 lanes/bank-group -> free (m136).
// ---------------------------------------------------------------------------
template <int K, int MT, bool OUT_F32>
__global__ __launch_bounds__(256) void cbr_bf16in(
    const ushort* __restrict__ Wb, const ushort* __restrict__ X,
    const float* __restrict__ sc, const float* __restrict__ bi,
    void* __restrict__ Yv)
{
    constexpr int O = MT * 128;
    __shared__ __align__(16) ushort As[2][4096];
    __shared__ __align__(16) ushort Bs[2][4096];

    const int tid = threadIdx.x;
    // bijective XCD-chunked swizzle (grid = MT*128*8, multiple of 8)
    const unsigned bid = blockIdx.x;
    const unsigned swz = (bid & 7) * (gridDim.x >> 3) + (bid >> 3);
    const int m0 = (int)(swz % MT) * 128;
    const int n0 = (int)((swz / MT) & 127) * 128;
    const int b  = (int)(swz / (MT * 128));

    const int wave = tid >> 6, lane = tid & 63;
    const int quad = lane >> 4, l15 = lane & 15;
    const int mq = (wave & 1) * 64, nq = (wave >> 1) * 64;

    // staging source map: thread t loads row=t>>1, octet j = 2q + jx
    const int row = tid >> 1;
    const int jx  = (tid & 1) ^ ((tid >> 3) & 1);
    const ushort* aW = Wb + (size_t)(m0 + row) * K + jx * 8;
    const ushort* aX = X + ((size_t)b * P_ + n0 + row) * K + jx * 8;

    f32x4 acc[4][4];
#pragma unroll
    for (int i = 0; i < 4; ++i)
#pragma unroll
        for (int j = 0; j < 4; ++j) acc[i][j] = {0.f, 0.f, 0.f, 0.f};

    auto stage = [&](int buf, int k0) {
        const ushort* ga = aW + k0;
        const ushort* gb = aX + k0;
        ushort* la = &As[buf][wave * 512];
        ushort* lb = &Bs[buf][wave * 512];
        gll16(ga,      la);              // pass q=0 (octets 0,1 swizzled)
        gll16(ga + 16, la + 2048);       // pass q=1 (octets 2,3 swizzled)
        gll16(gb,      lb);
        gll16(gb + 16, lb + 2048);
    };

    stage(0, 0);
    __syncthreads();                     // drains vmcnt(0): buf0 ready

    // fragment-read swizzle base (invariant): quad -> k-octet
    const int xb = (quad >> 1) * 2048 + ((((quad & 1) ^ ((l15 >> 2) & 1))) << 3);

    constexpr int NSTEP = K / 32;
#pragma unroll
    for (int t = 0; t < NSTEP; ++t) {
        if (t + 1 < NSTEP) stage((t + 1) & 1, (t + 1) * 32);   // prefetch next
        const ushort* as = &As[t & 1][0];
        const ushort* bs = &Bs[t & 1][0];
        frag8 af[4], bfv[4];
#pragma unroll
        for (int f = 0; f < 4; ++f) {
            af[f]  = *(const frag8*)(as + xb + (mq + f * 16 + l15) * 16);
            bfv[f] = *(const frag8*)(bs + xb + (nq + f * 16 + l15) * 16);
        }
#pragma unroll
        for (int i = 0; i < 4; ++i)
#pragma unroll
            for (int j = 0; j < 4; ++j)
                acc[i][j] = __builtin_amdgcn_mfma_f32_16x16x32_bf16(
                    af[i], bfv[j], acc[i][j], 0, 0, 0);
        __syncthreads();   // drains this iter's stage (vmcnt 0) + read-done
    }

    // epilogue
#pragma unroll
    for (int i = 0; i < 4; ++i) {
        const int o0 = m0 + mq + i * 16 + quad * 4;
        float s4[4], b4[4];
#pragma unroll
        for (int r = 0; r < 4; ++r) { s4[r] = sc[o0 + r]; b4[r] = bi[o0 + r]; }
#pragma unroll
        for (int j = 0; j < 4; ++j) {
            const int p = n0 + nq + j * 16 + l15;
            float v0 = fmaxf(fmaf(acc[i][j][0], s4[0], b4[0]), 0.f);
            float v1 = fmaxf(fmaf(acc[i][j][1], s4[1], b4[1]), 0.f);
            float v2 = fmaxf(fmaf(acc[i][j][2], s4[2], b4[2]), 0.f);
            float v3 = fmaxf(fmaf(acc[i][j][3], s4[3], b4[3]), 0.f);
            if constexpr (OUT_F32) {
                float* Yf = (float*)Yv;
                Yf[((size_t)b * O + o0 + 0) * P_ + p] = v0;
                Yf[((size_t)b * O + o0 + 1) * P_ + p] = v1;
                Yf[((size_t)b * O + o0 + 2) * P_ + p] = v2;
                Yf[((size_t)b * O + o0 + 3) * P_ + p] = v3;
            } else {
                uint2 w; w.x = pk_bf16(v0, v1); w.y = pk_bf16(v2, v3);
                *(uint2*)((ushort*)Yv + ((size_t)b * P_ + p) * O + o0) = w;
            }
        }
    }
}

// ---------------------------------------------------------------------------
// Attention on pixel-major q2 [B][P][KC] bf16, in-place -> ctx.
// 1 pixel per thread: Q row is 512 contiguous bytes (32 x 16B loads).
// Grid 512 blocks (2 blocks/CU -> 8 waves/CU vs 4 before).
// ---------------------------------------------------------------------------
__global__ __launch_bounds__(256) void attn_kernel(
    ushort* __restrict__ Q, const float* __restrict__ Kg, const float* __restrict__ Vg)
{
    __shared__ float kS[KC_ * M_];
    __shared__ float vS[KC_ * M_];
    const int b = blockIdx.y;
    const int p = blockIdx.x * 256 + threadIdx.x;
    for (int i = threadIdx.x; i < KC_ * M_; i += 256) {
        kS[i] = Kg[(size_t)b * KC_ * M_ + i];
        vS[i] = Vg[(size_t)b * KC_ * M_ + i];
    }
    __syncthreads();

    u16x8* Qr = reinterpret_cast<u16x8*>(Q + ((size_t)b * P_ + p) * KC_);

    float s[M_];
#pragma unroll
    for (int m = 0; m < M_; ++m) s[m] = 0.f;

    for (int g = 0; g < KC_ / 8; ++g) {
        u16x8 u = Qr[g];
#pragma unroll
        for (int e = 0; e < 8; ++e) {
            float q = bf16_f((ushort)u[e]);
            const float* kr = kS + (g * 8 + e) * M_;
#pragma unroll
            for (int m = 0; m < M_; ++m) s[m] = fmaf(q, kr[m], s[m]);
        }
    }

    float mx = -1e30f;
#pragma unroll
    for (int m = 0; m < M_; ++m) { s[m] *= 0.0625f; mx = fmaxf(mx, s[m]); }
    float sum = 0.f;
#pragma unroll
    for (int m = 0; m < M_; ++m) { s[m] = __expf(s[m] - mx); sum += s[m]; }
    const float inv = 1.f / sum;
#pragma unroll
    for (int m = 0; m < M_; ++m) s[m] *= inv;

    for (int g = 0; g < KC_ / 8; ++g) {
        u16x8 o;
#pragma unroll
        for (int e = 0; e < 8; ++e) {
            const float* vr = vS + (g * 8 + e) * M_;
            float a = 0.f;
#pragma unroll
            for (int m = 0; m < M_; ++m) a = fmaf(s[m], vr[m], a);
            o[e] = (short)bf16_1(a);
        }
        Qr[g] = o;
    }
}

// ---------------------------------------------------------------------------
// Launch. Scratch:
//   d_ws[  0 ..  64MB) : q1  bf16 [B][P][KC] (pixel-major)
//   d_ws[ 64 .. 128MB) : q2/ctx bf16 [B][P][KC] (in-place attention)
//   d_ws[128MB .. +640KB): bf16 weights W_p1, W_p2, W_u
//   d_out[0 ..)        : K,V fp32 scratch (dead before final GEMM overwrites)
// ---------------------------------------------------------------------------
extern "C" void kernel_launch(void* const* d_in, const int* in_sizes, int n_in,
                              void* d_out, int out_size, void* d_ws, size_t ws_size,
                              hipStream_t stream)
{
    const float* x     = (const float*)d_in[0];
    const float* proxy = (const float*)d_in[1];
    const float* W_p1  = (const float*)d_in[2];
    const float* W_p2  = (const float*)d_in[3];
    const float* W_o1  = (const float*)d_in[4];
    const float* W_o2  = (const float*)d_in[5];
    const float* W_d1  = (const float*)d_in[6];
    const float* W_d2  = (const float*)d_in[7];
    const float* W_u   = (const float*)d_in[8];
    const float* s_p1  = (const float*)d_in[9];  const float* b_p1 = (const float*)d_in[10];
    const float* s_p2  = (const float*)d_in[11]; const float* b_p2 = (const float*)d_in[12];
    const float* s_o1  = (const float*)d_in[13]; const float* b_o1 = (const float*)d_in[14];
    const float* s_o2  = (const float*)d_in[15]; const float* b_o2 = (const float*)d_in[16];
    const float* s_d1  = (const float*)d_in[17]; const float* b_d1 = (const float*)d_in[18];
    const float* s_d2  = (const float*)d_in[19]; const float* b_d2 = (const float*)d_in[20];
    const float* s_u   = (const float*)d_in[21]; const float* b_u  = (const float*)d_in[22];

    float* out = (float*)d_out;
    float* Kg  = out;                          // scratch in d_out
    float* Vg  = Kg + (size_t)B_ * KC_ * M_;
    ushort* q1   = (ushort*)d_ws;
    ushort* q2   = q1 + (size_t)B_ * KC_ * P_;   // +64 MB
    ushort* Wp1b = q2 + (size_t)B_ * KC_ * P_;   // +128 MB
    ushort* Wp2b = Wp1b + (size_t)KC_ * C_;
    ushort* Wub  = Wp2b + (size_t)KC_ * KC_;

    // 1) k/v projections (2x block-parallel) + weight bf16 conversion, fused
    front_kernel<<<dim3(176), dim3(256), 0, stream>>>(
        proxy, W_o1, s_o1, b_o1, W_o2, s_o2, b_o2,
               W_d1, s_d1, b_d1, W_d2, s_d2, b_d2, Kg, Vg,
        W_p1, W_p2, W_u, Wp1b, Wp2b, Wub);

    // 2) q1 = CBR(x, W_p1)   fp32 in, bf16 pixel-major out, K=512
    cbr_f32in<<<dim3(2 * 128 * B_), dim3(256), 0, stream>>>(
        Wp1b, x, s_p1, b_p1, q1);

    // 3) q2 = CBR(q1, W_p2)  bf16 gll GEMM, K=256, O=256, pixel-major out
    cbr_bf16in<KC_, 2, false><<<dim3(2 * 128 * B_), dim3(256), 0, stream>>>(
        Wp2b, q1, s_p2, b_p2, q2);

    // 4) attention: q2 -> ctx in place
    attn_kernel<<<dim3(P_ / 256, B_), dim3(256), 0, stream>>>(q2, Kg, Vg);

    // 5) out = CBR(ctx, W_u) bf16 gll GEMM, K=256, O=512, fp32 [B][C][P] out
    cbr_bf16in<KC_, 4, true><<<dim3(4 * 128 * B_), dim3(256), 0, stream>>>(
        Wub, q2, s_u, b_u, out);
}

// Round 2
// 778.425 us; speedup vs baseline: 1.1417x; 1.0192x over previous
//
#include <hip/hip_runtime.h>
#include <hip/hip_bf16.h>
#include <cstddef>
#include <cstdint>

// Problem constants
constexpr int B_  = 8;
constexpr int C_  = 512;
constexpr int KC_ = 256;
constexpr int M_  = 19;
constexpr int P_  = 128 * 128;  // 16384 pixels

typedef short frag8 __attribute__((ext_vector_type(8)));           // 8 bf16 (4 VGPRs)
typedef float f32x4 __attribute__((ext_vector_type(4)));           // 4 fp32 acc
typedef unsigned short u16x8 __attribute__((ext_vector_type(8)));  // 8 bf16

__device__ __forceinline__ unsigned pk_bf16(float a, float b) {
    union { __hip_bfloat162 h; unsigned u; } cv;
    cv.h = __float22bfloat162_rn(make_float2(a, b));
    return cv.u;
}
__device__ __forceinline__ ushort bf16_1(float a) {
    union { __hip_bfloat16 h; ushort u; } cv;
    cv.h = __float2bfloat16(a);
    return cv.u;
}
__device__ __forceinline__ float bf16_f(ushort u) {
    return __uint_as_float(((unsigned)u) << 16);
}

// global(16B per lane, per-lane address) -> LDS (wave-uniform base + lane*16)
__device__ __forceinline__ void gll16(const ushort* g, ushort* l) {
    __builtin_amdgcn_global_load_lds(
        (__attribute__((address_space(1))) void*)(ushort*)g,
        (__attribute__((address_space(3))) void*)l, 16, 0, 0);
}

// ---------------------------------------------------------------------------
// k/v projection (fp32, tiny): proxy [B,C,M] -> K,V [B,KC,M]
// ---------------------------------------------------------------------------
__device__ __forceinline__ void two_stage_proj(
    const float* __restrict__ pS, float* __restrict__ t1,
    const float* __restrict__ W1, const float* __restrict__ s1, const float* __restrict__ b1,
    const float* __restrict__ W2, const float* __restrict__ s2, const float* __restrict__ b2,
    float* __restrict__ outg, int b, int tid)
{
    float acc[M_];
#pragma unroll
    for (int m = 0; m < M_; ++m) acc[m] = 0.f;
    const float4* wrow = reinterpret_cast<const float4*>(W1 + (size_t)tid * C_);
    for (int c4 = 0; c4 < C_ / 4; ++c4) {
        float4 w = wrow[c4];
        const float* pr = pS + c4 * 4 * M_;
#pragma unroll
        for (int m = 0; m < M_; ++m) acc[m] = fmaf(w.x, pr[m], acc[m]);
#pragma unroll
        for (int m = 0; m < M_; ++m) acc[m] = fmaf(w.y, pr[M_ + m], acc[m]);
#pragma unroll
        for (int m = 0; m < M_; ++m) acc[m] = fmaf(w.z, pr[2 * M_ + m], acc[m]);
#pragma unroll
        for (int m = 0; m < M_; ++m) acc[m] = fmaf(w.w, pr[3 * M_ + m], acc[m]);
    }
    float s = s1[tid], bb = b1[tid];
    __syncthreads();
#pragma unroll
    for (int m = 0; m < M_; ++m) t1[tid * M_ + m] = fmaxf(fmaf(acc[m], s, bb), 0.f);
    __syncthreads();
#pragma unroll
    for (int m = 0; m < M_; ++m) acc[m] = 0.f;
    const float4* wrow2 = reinterpret_cast<const float4*>(W2 + (size_t)tid * KC_);
    for (int c4 = 0; c4 < KC_ / 4; ++c4) {
        float4 w = wrow2[c4];
        const float* tr = t1 + c4 * 4 * M_;
#pragma unroll
        for (int m = 0; m < M_; ++m) acc[m] = fmaf(w.x, tr[m], acc[m]);
#pragma unroll
        for (int m = 0; m < M_; ++m) acc[m] = fmaf(w.y, tr[M_ + m], acc[m]);
#pragma unroll
        for (int m = 0; m < M_; ++m) acc[m] = fmaf(w.z, tr[2 * M_ + m], acc[m]);
#pragma unroll
        for (int m = 0; m < M_; ++m) acc[m] = fmaf(w.w, tr[3 * M_ + m], acc[m]);
    }
    s = s2[tid]; bb = b2[tid];
#pragma unroll
    for (int m = 0; m < M_; ++m)
        outg[((size_t)b * KC_ + tid) * M_ + m] = fmaxf(fmaf(acc[m], s, bb), 0.f);
}

__device__ __forceinline__ void cvt_w(const float* __restrict__ s, ushort* __restrict__ d,
                                      int n4, int cid, int nb) {
    for (int i = cid * 256 + (int)threadIdx.x; i < n4; i += nb * 256) {
        float4 f = ((const float4*)s)[i];
        ushort4 h;
        h.x = bf16_1(f.x); h.y = bf16_1(f.y); h.z = bf16_1(f.z); h.w = bf16_1(f.w);
        ((ushort4*)d)[i] = h;
    }
}

// Fused front: blocks 0..15 do K/V projections; blocks 16.. convert weights.
__global__ __launch_bounds__(256) void front_kernel(
    const float* __restrict__ proxy,
    const float* __restrict__ Wo1, const float* __restrict__ so1, const float* __restrict__ bo1,
    const float* __restrict__ Wo2, const float* __restrict__ so2, const float* __restrict__ bo2,
    const float* __restrict__ Wd1, const float* __restrict__ sd1, const float* __restrict__ bd1,
    const float* __restrict__ Wd2, const float* __restrict__ sd2, const float* __restrict__ bd2,
    float* __restrict__ Kg, float* __restrict__ Vg,
    const float* __restrict__ Wp1f, const float* __restrict__ Wp2f, const float* __restrict__ Wuf,
    ushort* __restrict__ Wp1b, ushort* __restrict__ Wp2b, ushort* __restrict__ Wub)
{
    __shared__ float pS[C_ * M_];
    __shared__ float t1[KC_ * M_];
    const int bx = blockIdx.x, tid = threadIdx.x;
    if (bx < 16) {
        const int b = bx >> 1;
        for (int i = tid; i < C_ * M_; i += 256) pS[i] = proxy[(size_t)b * C_ * M_ + i];
        __syncthreads();
        if (bx & 1)
            two_stage_proj(pS, t1, Wd1, sd1, bd1, Wd2, sd2, bd2, Vg, b, tid);
        else
            two_stage_proj(pS, t1, Wo1, so1, bo1, Wo2, so2, bo2, Kg, b, tid);
    } else {
        const int cid = bx - 16, nb = (int)gridDim.x - 16;
        cvt_w(Wp1f, Wp1b, KC_ * C_ / 4, cid, nb);
        cvt_w(Wp2f, Wp2b, KC_ * KC_ / 4, cid, nb);
        cvt_w(Wuf,  Wub,  C_ * KC_ / 4, cid, nb);
    }
}

// ---------------------------------------------------------------------------
// Step 2: q1 = CBR(x, W_p1).  W bf16 [O][K] via gll (double-buffered LDS),
// X fp32 [B][C][P] reg-staged (cvt to bf16) with 1-iter-ahead reg prefetch.
// 256x128 tile (full O per block -> X read ONCE), 512 threads, 8 waves
// (4 m-quads x 2 n-halves, 64x64 each). Counted-vmcnt raw-barrier pipeline:
// outstanding = A(t):2 + B(t+1):4 + A(t+1):2 -> s_waitcnt vmcnt(6) retires
// exactly A(t); never drains the prefetch.  Output q1 [B][P][KC] bf16.
// ---------------------------------------------------------------------------
__global__ __launch_bounds__(512, 4) void cbr_f32in(
    const ushort* __restrict__ Wb, const float* __restrict__ X,
    const float* __restrict__ sc, const float* __restrict__ bi,
    ushort* __restrict__ Y)
{
    constexpr int K = C_;   // 512
    constexpr int O = KC_;  // 256
    // A: [buf][pass(2)][row*16 + slot*8], 256 rows, gll-linear + XOR swizzle
    __shared__ __align__(16) ushort As[2][8192];
    // B: reg-staged, pitch 40 (2-way alias free on frag reads)
    __shared__ __align__(16) ushort Bs[128][40];

    const int tid = threadIdx.x;
    const unsigned bid = blockIdx.x;                 // grid 1024 = 8 XCD * 128
    const unsigned swz = (bid & 7) * (gridDim.x >> 3) + (bid >> 3);
    const int n0 = (int)(swz & 127) * 128;
    const int b  = (int)(swz >> 7);                  // one batch per XCD chunk

    const int wave = tid >> 6, lane = tid & 63;
    const int quad = lane >> 4, l15 = lane & 15;
    const int mq = (wave >> 1) * 64, nq = (wave & 1) * 64;

    // A staging: row = tid>>1 (0..255), slot = tid&1, src octet = slot^((row>>2)&1)
    const int jx = (tid & 1) ^ ((tid >> 3) & 1);
    const ushort* aW = Wb + (size_t)(tid >> 1) * K + jx * 8;
    // B staging: pixel pair pp, k rows kg..kg+3
    const int pp = (tid & 63) * 2;
    const int kg = (tid >> 6) * 4;
    const float* Xf = X + (size_t)b * K * P_ + n0 + pp;

    f32x4 acc[4][4];
#pragma unroll
    for (int i = 0; i < 4; ++i)
#pragma unroll
        for (int j = 0; j < 4; ++j) acc[i][j] = {0.f, 0.f, 0.f, 0.f};

    float2 xr[4];
    auto loadB = [&](int k0) {
#pragma unroll
        for (int j = 0; j < 4; ++j)
            xr[j] = *(const float2*)(Xf + (size_t)(k0 + kg + j) * P_);
    };
    auto stageA = [&](int buf, int k0) {
        const ushort* g = aW + k0;
        ushort* l = &As[buf][wave * 512];
        gll16(g,      l);           // pass0: k 0-15 of this step
        gll16(g + 16, l + 4096);    // pass1: k 16-31
    };

    loadB(0);
    stageA(0, 0);
    // A fragment read base: pass = quad>>1, slot = (quad&1)^((l15>>2)&1)
    const int axb = (quad >> 1) * 4096 + ((((quad & 1) ^ ((l15 >> 2) & 1))) << 3);

    auto body = [&](int t, bool pf) {
        // pack B(t) from regs (compiler auto-waits exactly B(t)'s vmcnt)
        unsigned bd0[2], bd1[2];
        bd0[0] = pk_bf16(xr[0].x, xr[1].x); bd0[1] = pk_bf16(xr[2].x, xr[3].x);
        bd1[0] = pk_bf16(xr[0].y, xr[1].y); bd1[1] = pk_bf16(xr[2].y, xr[3].y);
        asm volatile("s_waitcnt lgkmcnt(0)" ::: "memory");  // prev LDS reads drained
        __builtin_amdgcn_s_barrier();                        // Bs free to overwrite
        *(uint2*)(&Bs[pp][kg])     = *(uint2*)bd0;
        *(uint2*)(&Bs[pp + 1][kg]) = *(uint2*)bd1;
        if (pf) {
            loadB((t + 1) * 32);
            stageA((t + 1) & 1, (t + 1) * 32);
            asm volatile("s_waitcnt vmcnt(6)" ::: "memory"); // A(t) landed
        } else {
            asm volatile("s_waitcnt vmcnt(0)" ::: "memory");
        }
        asm volatile("s_waitcnt lgkmcnt(0)" ::: "memory");   // Bs writes visible
        __builtin_amdgcn_s_barrier();

        const ushort* as = &As[t & 1][0];
        frag8 af[4], bfv[4];
#pragma unroll
        for (int f = 0; f < 4; ++f) {
            af[f]  = *(const frag8*)(as + axb + (mq + f * 16 + l15) * 16);
            bfv[f] = *(const frag8*)(&Bs[nq + f * 16 + l15][quad * 8]);
        }
#pragma unroll
        for (int i = 0; i < 4; ++i)
#pragma unroll
            for (int j = 0; j < 4; ++j)
                acc[i][j] = __builtin_amdgcn_mfma_f32_16x16x32_bf16(
                    af[i], bfv[j], acc[i][j], 0, 0, 0);
    };

    for (int t = 0; t < K / 32 - 1; ++t) body(t, true);
    body(K / 32 - 1, false);

    // epilogue: relu(s*acc+b) -> Y[b][p][o] bf16
#pragma unroll
    for (int i = 0; i < 4; ++i) {
        const int o0 = mq + i * 16 + quad * 4;
        float s4[4], b4[4];
#pragma unroll
        for (int r = 0; r < 4; ++r) { s4[r] = sc[o0 + r]; b4[r] = bi[o0 + r]; }
#pragma unroll
        for (int j = 0; j < 4; ++j) {
            const int p = n0 + nq + j * 16 + l15;
            float v0 = fmaxf(fmaf(acc[i][j][0], s4[0], b4[0]), 0.f);
            float v1 = fmaxf(fmaf(acc[i][j][1], s4[1], b4[1]), 0.f);
            float v2 = fmaxf(fmaf(acc[i][j][2], s4[2], b4[2]), 0.f);
            float v3 = fmaxf(fmaf(acc[i][j][3], s4[3], b4[3]), 0.f);
            uint2 w; w.x = pk_bf16(v0, v1); w.y = pk_bf16(v2, v3);
            *(uint2*)(Y + ((size_t)b * P_ + p) * O + o0) = w;
        }
    }
}

// ---------------------------------------------------------------------------
// Steps 3 & 5: full-gll CBR-GEMM, counted-vmcnt raw-barrier pipeline (T4).
// W bf16 [O][K] row-major, X bf16 [B][P][K] pixel-major. 128x128 tile, BK=32,
// double-buffered.  Per iter: stage(t+1) -> vmcnt(4) [stage(t) landed] ->
// barrier -> ds_read+MFMA -> lgkmcnt(0) -> barrier.  Never vmcnt(0) in loop.
// ---------------------------------------------------------------------------
template <int K, int MT, bool OUT_F32>
__global__ __launch_bounds__(256) void cbr_bf16in(
    const ushort* __restrict__ Wb, const ushort* __restrict__ X,
    const float* __restrict__ sc, const float* __restrict__ bi,
    void* __restrict__ Yv)
{
    constexpr int O = MT * 128;
    __shared__ __align__(16) ushort As[2][4096];
    __shared__ __align__(16) ushort Bs[2][4096];

    const int tid = threadIdx.x;
    const unsigned bid = blockIdx.x;
    const unsigned swz = (bid & 7) * (gridDim.x >> 3) + (bid >> 3);
    const int m0 = (int)(swz % MT) * 128;
    const int n0 = (int)((swz / MT) & 127) * 128;
    const int b  = (int)(swz / (MT * 128));

    const int wave = tid >> 6, lane = tid & 63;
    const int quad = lane >> 4, l15 = lane & 15;
    const int mq = (wave & 1) * 64, nq = (wave >> 1) * 64;

    const int row = tid >> 1;
    const int jx  = (tid & 1) ^ ((tid >> 3) & 1);
    const ushort* aW = Wb + (size_t)(m0 + row) * K + jx * 8;
    const ushort* aX = X + ((size_t)b * P_ + n0 + row) * K + jx * 8;

    f32x4 acc[4][4];
#pragma unroll
    for (int i = 0; i < 4; ++i)
#pragma unroll
        for (int j = 0; j < 4; ++j) acc[i][j] = {0.f, 0.f, 0.f, 0.f};

    auto stage = [&](int buf, int k0) {
        const ushort* ga = aW + k0;
        const ushort* gb = aX + k0;
        ushort* la = &As[buf][wave * 512];
        ushort* lb = &Bs[buf][wave * 512];
        gll16(ga,      la);
        gll16(ga + 16, la + 2048);
        gll16(gb,      lb);
        gll16(gb + 16, lb + 2048);
    };

    stage(0, 0);

    const int xb = (quad >> 1) * 2048 + ((((quad & 1) ^ ((l15 >> 2) & 1))) << 3);

    constexpr int NSTEP = K / 32;
#pragma unroll
    for (int t = 0; t < NSTEP; ++t) {
        if (t + 1 < NSTEP) {
            stage((t + 1) & 1, (t + 1) * 32);
            asm volatile("s_waitcnt vmcnt(4)" ::: "memory");  // stage(t) landed
        } else {
            asm volatile("s_waitcnt vmcnt(0)" ::: "memory");
        }
        __builtin_amdgcn_s_barrier();                          // all waves' stage(t) done

        const ushort* as = &As[t & 1][0];
        const ushort* bs = &Bs[t & 1][0];
        frag8 af[4], bfv[4];
#pragma unroll
        for (int f = 0; f < 4; ++f) {
            af[f]  = *(const frag8*)(as + xb + (mq + f * 16 + l15) * 16);
            bfv[f] = *(const frag8*)(bs + xb + (nq + f * 16 + l15) * 16);
        }
#pragma unroll
        for (int i = 0; i < 4; ++i)
#pragma unroll
            for (int j = 0; j < 4; ++j)
                acc[i][j] = __builtin_amdgcn_mfma_f32_16x16x32_bf16(
                    af[i], bfv[j], acc[i][j], 0, 0, 0);

        asm volatile("s_waitcnt lgkmcnt(0)" ::: "memory");     // reads drained
        __builtin_amdgcn_s_barrier();                          // before buf reuse
    }

    // epilogue
#pragma unroll
    for (int i = 0; i < 4; ++i) {
        const int o0 = m0 + mq + i * 16 + quad * 4;
        float s4[4], b4[4];
#pragma unroll
        for (int r = 0; r < 4; ++r) { s4[r] = sc[o0 + r]; b4[r] = bi[o0 + r]; }
#pragma unroll
        for (int j = 0; j < 4; ++j) {
            const int p = n0 + nq + j * 16 + l15;
            float v0 = fmaxf(fmaf(acc[i][j][0], s4[0], b4[0]), 0.f);
            float v1 = fmaxf(fmaf(acc[i][j][1], s4[1], b4[1]), 0.f);
            float v2 = fmaxf(fmaf(acc[i][j][2], s4[2], b4[2]), 0.f);
            float v3 = fmaxf(fmaf(acc[i][j][3], s4[3], b4[3]), 0.f);
            if constexpr (OUT_F32) {
                float* Yf = (float*)Yv;
                Yf[((size_t)b * O + o0 + 0) * P_ + p] = v0;
                Yf[((size_t)b * O + o0 + 1) * P_ + p] = v1;
                Yf[((size_t)b * O + o0 + 2) * P_ + p] = v2;
                Yf[((size_t)b * O + o0 + 3) * P_ + p] = v3;
            } else {
                uint2 w; w.x = pk_bf16(v0, v1); w.y = pk_bf16(v2, v3);
                *(uint2*)((ushort*)Yv + ((size_t)b * P_ + p) * O + o0) = w;
            }
        }
    }
}

// ---------------------------------------------------------------------------
// Attention on pixel-major q2 [B][P][KC] bf16, in-place -> ctx.
// ---------------------------------------------------------------------------
__global__ __launch_bounds__(256) void attn_kernel(
    ushort* __restrict__ Q, const float* __restrict__ Kg, const float* __restrict__ Vg)
{
    __shared__ float kS[KC_ * M_];
    __shared__ float vS[KC_ * M_];
    const int b = blockIdx.y;
    const int p = blockIdx.x * 256 + threadIdx.x;
    for (int i = threadIdx.x; i < KC_ * M_; i += 256) {
        kS[i] = Kg[(size_t)b * KC_ * M_ + i];
        vS[i] = Vg[(size_t)b * KC_ * M_ + i];
    }
    __syncthreads();

    u16x8* Qr = reinterpret_cast<u16x8*>(Q + ((size_t)b * P_ + p) * KC_);

    float s[M_];
#pragma unroll
    for (int m = 0; m < M_; ++m) s[m] = 0.f;

    for (int g = 0; g < KC_ / 8; ++g) {
        u16x8 u = Qr[g];
#pragma unroll
        for (int e = 0; e < 8; ++e) {
            float q = bf16_f((ushort)u[e]);
            const float* kr = kS + (g * 8 + e) * M_;
#pragma unroll
            for (int m = 0; m < M_; ++m) s[m] = fmaf(q, kr[m], s[m]);
        }
    }

    float mx = -1e30f;
#pragma unroll
    for (int m = 0; m < M_; ++m) { s[m] *= 0.0625f; mx = fmaxf(mx, s[m]); }
    float sum = 0.f;
#pragma unroll
    for (int m = 0; m < M_; ++m) { s[m] = __expf(s[m] - mx); sum += s[m]; }
    const float inv = 1.f / sum;
#pragma unroll
    for (int m = 0; m < M_; ++m) s[m] *= inv;

    for (int g = 0; g < KC_ / 8; ++g) {
        u16x8 o;
#pragma unroll
        for (int e = 0; e < 8; ++e) {
            const float* vr = vS + (g * 8 + e) * M_;
            float a = 0.f;
#pragma unroll
            for (int m = 0; m < M_; ++m) a = fmaf(s[m], vr[m], a);
            o[e] = (short)bf16_1(a);
        }
        Qr[g] = o;
    }
}

// ---------------------------------------------------------------------------
// Launch. Scratch:
//   d_ws[  0 ..  64MB) : q1  bf16 [B][P][KC]
//   d_ws[ 64 .. 128MB) : q2/ctx bf16 [B][P][KC] (in-place attention)
//   d_ws[128MB .. +640KB): bf16 weights W_p1, W_p2, W_u
//   d_out[0 ..)        : K,V fp32 scratch (dead before final GEMM overwrites)
// ---------------------------------------------------------------------------
extern "C" void kernel_launch(void* const* d_in, const int* in_sizes, int n_in,
                              void* d_out, int out_size, void* d_ws, size_t ws_size,
                              hipStream_t stream)
{
    const float* x     = (const float*)d_in[0];
    const float* proxy = (const float*)d_in[1];
    const float* W_p1  = (const float*)d_in[2];
    const float* W_p2  = (const float*)d_in[3];
    const float* W_o1  = (const float*)d_in[4];
    const float* W_o2  = (const float*)d_in[5];
    const float* W_d1  = (const float*)d_in[6];
    const float* W_d2  = (const float*)d_in[7];
    const float* W_u   = (const float*)d_in[8];
    const float* s_p1  = (const float*)d_in[9];  const float* b_p1 = (const float*)d_in[10];
    const float* s_p2  = (const float*)d_in[11]; const float* b_p2 = (const float*)d_in[12];
    const float* s_o1  = (const float*)d_in[13]; const float* b_o1 = (const float*)d_in[14];
    const float* s_o2  = (const float*)d_in[15]; const float* b_o2 = (const float*)d_in[16];
    const float* s_d1  = (const float*)d_in[17]; const float* b_d1 = (const float*)d_in[18];
    const float* s_d2  = (const float*)d_in[19]; const float* b_d2 = (const float*)d_in[20];
    const float* s_u   = (const float*)d_in[21]; const float* b_u  = (const float*)d_in[22];

    float* out = (float*)d_out;
    float* Kg  = out;                          // scratch in d_out
    float* Vg  = Kg + (size_t)B_ * KC_ * M_;
    ushort* q1   = (ushort*)d_ws;
    ushort* q2   = q1 + (size_t)B_ * KC_ * P_;   // +64 MB
    ushort* Wp1b = q2 + (size_t)B_ * KC_ * P_;   // +128 MB
    ushort* Wp2b = Wp1b + (size_t)KC_ * C_;
    ushort* Wub  = Wp2b + (size_t)KC_ * KC_;

    // 1) k/v projections + weight bf16 conversion, fused
    front_kernel<<<dim3(176), dim3(256), 0, stream>>>(
        proxy, W_o1, s_o1, b_o1, W_o2, s_o2, b_o2,
               W_d1, s_d1, b_d1, W_d2, s_d2, b_d2, Kg, Vg,
        W_p1, W_p2, W_u, Wp1b, Wp2b, Wub);

    // 2) q1 = CBR(x, W_p1)   fp32 in, bf16 pixel-major out, K=512, 256x128 tile
    cbr_f32in<<<dim3(128 * B_), dim3(512), 0, stream>>>(
        Wp1b, x, s_p1, b_p1, q1);

    // 3) q2 = CBR(q1, W_p2)  bf16 gll GEMM, K=256, O=256, pixel-major out
    cbr_bf16in<KC_, 2, false><<<dim3(2 * 128 * B_), dim3(256), 0, stream>>>(
        Wp2b, q1, s_p2, b_p2, q2);

    // 4) attention: q2 -> ctx in place
    attn_kernel<<<dim3(P_ / 256, B_), dim3(256), 0, stream>>>(q2, Kg, Vg);

    // 5) out = CBR(ctx, W_u) bf16 gll GEMM, K=256, O=512, fp32 [B][C][P] out
    cbr_bf16in<KC_, 4, true><<<dim3(4 * 128 * B_), dim3(256), 0, stream>>>(
        Wub, q2, s_u, b_u, out);
}